// Round 4
// baseline (908.692 us; speedup 1.0000x reference)
//
#include <hip/hip_runtime.h>
#include <hip/hip_bf16.h>

using bf16 = __hip_bfloat16;
typedef __attribute__((ext_vector_type(8))) short short8;
typedef __attribute__((ext_vector_type(4))) float f32x4;
typedef __attribute__((ext_vector_type(4))) unsigned int uint4v;

// Problem constants
static constexpr int LB = 2;           // batch
static constexpr int LL = 1024;        // seq len
static constexpr int DM = 512;         // d_model
static constexpr int DI = 1024;        // d_inner
static constexpr int DSN = 16;         // d_state
static constexpr int RK = 32;          // dt_rank
static constexpr int MR_ROWS = LB * LL; // 2048 rows

// ---------------------------------------------------------------------------
// fp32 -> bf16 conversion, multi-segment in one launch
// ---------------------------------------------------------------------------
struct ConvArgs {
    const float* src[9];
    bf16*        dst[9];
    int          n4[9];
};

__global__ __launch_bounds__(256) void convert_bf16_multi(ConvArgs a) {
    const int s = blockIdx.y;
    const float4* __restrict__ src = (const float4*)a.src[s];
    bf16* __restrict__ dst = a.dst[s];
    const int n4 = a.n4[s];
    for (int i = blockIdx.x * 256 + threadIdx.x; i < n4; i += gridDim.x * 256) {
        float4 v = src[i];
        bf16 t[4] = {__float2bfloat16(v.x), __float2bfloat16(v.y),
                     __float2bfloat16(v.z), __float2bfloat16(v.w)};
        *(uint2*)(dst + (size_t)i * 4) = *(uint2*)t;
    }
}

// ---------------------------------------------------------------------------
// LayerNorm over last dim (512). One block (256 thr) per row, 2 elems/thread.
// ---------------------------------------------------------------------------
__device__ __forceinline__ void ln_store(float* outrow, int tid, float a, float b) {
    ((float2*)outrow)[tid] = make_float2(a, b);
}
__device__ __forceinline__ void ln_store(bf16* outrow, int tid, float a, float b) {
    __hip_bfloat162 h;
    h.x = __float2bfloat16(a);
    h.y = __float2bfloat16(b);
    ((__hip_bfloat162*)outrow)[tid] = h;
}

template <typename T>
__global__ __launch_bounds__(256) void ln_kernel(const float* __restrict__ x,
                                                 const float* __restrict__ w,
                                                 const float* __restrict__ b,
                                                 T* __restrict__ out) {
    const int row = blockIdx.x;
    const int tid = threadIdx.x;
    const int wid = tid >> 6, lane = tid & 63;
    __shared__ float red[8];

    const float2 v = ((const float2*)(x + (size_t)row * DM))[tid];
    float s = v.x + v.y;
#pragma unroll
    for (int m = 1; m < 64; m <<= 1) s += __shfl_xor(s, m);
    if (lane == 0) red[wid] = s;
    __syncthreads();
    const float mean = (red[0] + red[1] + red[2] + red[3]) * (1.f / DM);
    const float d0 = v.x - mean, d1 = v.y - mean;
    float s2 = d0 * d0 + d1 * d1;
#pragma unroll
    for (int m = 1; m < 64; m <<= 1) s2 += __shfl_xor(s2, m);
    if (lane == 0) red[4 + wid] = s2;
    __syncthreads();
    const float var = (red[4] + red[5] + red[6] + red[7]) * (1.f / DM);
    const float rs = rsqrtf(var + 1e-5f);
    const float2 wv = ((const float2*)w)[tid];
    const float2 bv = ((const float2*)b)[tid];
    ln_store(out + (size_t)row * DM, tid, d0 * rs * wv.x + bv.x, d1 * rs * wv.y + bv.y);
}

// ---------------------------------------------------------------------------
// GEMM: C[M,N] = A[M,K] * B[N,K]^T  (A,B bf16 row-major K-contiguous, C fp32)
// EPI: 0 = none, 1 = +bias[col], 2 = atomicAdd (split-K over blockIdx.z,
//      K arg = per-chunk K), 3 = += existing C (residual)
// LDS XOR-swizzle (T2): row stride is 128B (BK=64); byte ^= (row&7)<<4 on both
// the staging write and the fragment read.
// ---------------------------------------------------------------------------
template <int BM, int BN, int BK, int EPI>
__global__ __launch_bounds__(256) void gemm_bt(const bf16* __restrict__ A, int lda,
                                               const bf16* __restrict__ B, int ldb,
                                               float* __restrict__ C, int ldc,
                                               int K, const float* __restrict__ bias) {
    static_assert(BK == 64, "swizzle assumes 128B LDS row stride");
    constexpr int MR = (BM / 2) / 16;
    constexpr int NR = (BN / 2) / 16;
    __shared__ __align__(16) bf16 sA[BM * BK];
    __shared__ __align__(16) bf16 sB[BN * BK];

    const int tid = threadIdx.x;
    const int lane = tid & 63, wid = tid >> 6;
    const int wr = wid >> 1, wc = wid & 1;
    const int m0 = blockIdx.y * BM, n0 = blockIdx.x * BN;
    const int kbase = (EPI == 2) ? blockIdx.z * K : 0;

    f32x4 acc[MR][NR] = {};

    constexpr int A_LD = BM * BK * 2 / (256 * 16);
    constexpr int B_LD = BN * BK * 2 / (256 * 16);
    static_assert(A_LD >= 1 && B_LD >= 1, "tile too small");

    for (int k0 = kbase; k0 < kbase + K; k0 += BK) {
#pragma unroll
        for (int i = 0; i < A_LD; ++i) {
            const int byte = (tid + i * 256) * 16;
            const int row = byte / (BK * 2), colb = byte % (BK * 2);
            const int sw = colb ^ ((row & 7) << 4);
            *(uint4v*)((char*)sA + row * (BK * 2) + sw) =
                *(const uint4v*)((const char*)A + ((size_t)(m0 + row) * lda + k0) * 2 + colb);
        }
#pragma unroll
        for (int i = 0; i < B_LD; ++i) {
            const int byte = (tid + i * 256) * 16;
            const int row = byte / (BK * 2), colb = byte % (BK * 2);
            const int sw = colb ^ ((row & 7) << 4);
            *(uint4v*)((char*)sB + row * (BK * 2) + sw) =
                *(const uint4v*)((const char*)B + ((size_t)(n0 + row) * ldb + k0) * 2 + colb);
        }
        __syncthreads();
#pragma unroll
        for (int kk = 0; kk < BK; kk += 32) {
            const int kb2 = (kk + (lane >> 4) * 8) * 2; // byte col, 16B aligned
            short8 af[MR], bfr[NR];
#pragma unroll
            for (int m = 0; m < MR; ++m) {
                const int r = wr * (BM / 2) + m * 16 + (lane & 15);
                af[m] = *(const short8*)((const char*)sA + r * (BK * 2) + (kb2 ^ ((r & 7) << 4)));
            }
#pragma unroll
            for (int n = 0; n < NR; ++n) {
                const int r = wc * (BN / 2) + n * 16 + (lane & 15);
                bfr[n] = *(const short8*)((const char*)sB + r * (BK * 2) + (kb2 ^ ((r & 7) << 4)));
            }
#pragma unroll
            for (int m = 0; m < MR; ++m) {
#pragma unroll
                for (int n = 0; n < NR; ++n) {
                    acc[m][n] = __builtin_amdgcn_mfma_f32_16x16x32_bf16(af[m], bfr[n], acc[m][n], 0, 0, 0);
                }
            }
        }
        __syncthreads();
    }

#pragma unroll
    for (int m = 0; m < MR; ++m) {
#pragma unroll
        for (int n = 0; n < NR; ++n) {
            const int col = n0 + wc * (BN / 2) + n * 16 + (lane & 15);
            const float bv = (EPI == 1) ? bias[col] : 0.f;
#pragma unroll
            for (int j = 0; j < 4; ++j) {
                const int row = m0 + wr * (BM / 2) + m * 16 + (lane >> 4) * 4 + j;
                float v = acc[m][n][j] + bv;
                float* p = C + (size_t)row * ldc + col;
                if (EPI == 2) {
                    atomicAdd(p, v);
                } else {
                    if (EPI == 3) v += *p;
                    *p = v;
                }
            }
        }
    }
}

// ---------------------------------------------------------------------------
// Fused causal conv(K=4)+SiLU with transposed outputs, tiled 64 rows x 64 ch.
// Writes: xc_bf[row][c] (bf16, for xp-GEMM), xc_t[c][row] (fp32, for scan),
//         zs_t[c][row] = silu(z) (fp32, for scan).
// ---------------------------------------------------------------------------
__global__ __launch_bounds__(256) void conv_silu_T(const float* __restrict__ xz,
                                                   const float* __restrict__ cw,
                                                   const float* __restrict__ cb,
                                                   bf16* __restrict__ xc_bf,
                                                   float* __restrict__ xc_t,
                                                   float* __restrict__ zs_t) {
    const int c0 = blockIdx.x * 64;
    const int r0 = blockIdx.y * 64;
    const int bstart = (r0 >> 10) << 10; // batch start row (zero-pad boundary)
    const int tid = threadIdx.x;

    __shared__ float sx[67 * 64];     // rows r0-3 .. r0+63
    __shared__ float T[64 * 65];      // transpose buffer [c][r], stride 65

    // stage x-half tile + 3 halo rows (coalesced float4)
    for (int idx = tid; idx < 67 * 16; idx += 256) {
        const int rr = idx >> 4, f4 = idx & 15;
        const int row = r0 - 3 + rr;
        float4 v = make_float4(0.f, 0.f, 0.f, 0.f);
        if (row >= bstart)
            v = *(const float4*)(xz + (size_t)row * (2 * DI) + c0 + f4 * 4);
        *(float4*)(sx + rr * 64 + f4 * 4) = v;
    }
    __syncthreads();

    // compute conv+silu: c fixed per thread, r = rgrp + 4*i
    const int c = tid & 63;
    const int rgrp = tid >> 6;
    const float4 w = *(const float4*)(cw + (size_t)(c0 + c) * 4);
    const float cbv = cb[c0 + c];
#pragma unroll
    for (int i = 0; i < 16; ++i) {
        const int r = rgrp + i * 4;
        float acc = cbv + w.w * sx[(r + 3) * 64 + c] + w.z * sx[(r + 2) * 64 + c]
                        + w.y * sx[(r + 1) * 64 + c] + w.x * sx[(r + 0) * 64 + c];
        const float s = acc / (1.f + expf(-acc));
        xc_bf[(size_t)(r0 + r) * DI + c0 + c] = __float2bfloat16(s);
        T[c * 65 + r] = s;
    }
    __syncthreads();
#pragma unroll
    for (int i = 0; i < 16; ++i) {
        const int idx = tid + i * 256;
        const int cc = idx >> 6, r = idx & 63;
        xc_t[(size_t)(c0 + cc) * MR_ROWS + r0 + r] = T[cc * 65 + r];
    }
    __syncthreads();

    // z-half: silu only, via transpose buffer
#pragma unroll
    for (int i = 0; i < 16; ++i) {
        const int r = rgrp + i * 4;
        const float zv = xz[(size_t)(r0 + r) * (2 * DI) + DI + c0 + c];
        T[c * 65 + r] = zv / (1.f + expf(-zv));
    }
    __syncthreads();
#pragma unroll
    for (int i = 0; i < 16; ++i) {
        const int idx = tid + i * 256;
        const int cc = idx >> 6, r = idx & 63;
        zs_t[(size_t)(c0 + cc) * MR_ROWS + r0 + r] = T[cc * 65 + r];
    }
}

// ---------------------------------------------------------------------------
// delta_t[c][row] = softplus(dt[row] @ dt_w[c] + dt_b[c]); tiled 64x64 with
// LDS transpose. Also (c0==0 blocks): transpose dbc[:,32:64] -> bct[32][rows]
// so the scan can read B/C as contiguous per-thread streams.
// ---------------------------------------------------------------------------
__global__ __launch_bounds__(256) void dtproj_T(const float* __restrict__ dbc,
                                                const float* __restrict__ dtw,
                                                const float* __restrict__ dtb,
                                                float* __restrict__ delta_t,
                                                float* __restrict__ bct) {
    const int c0 = blockIdx.x * 64;
    const int r0 = blockIdx.y * 64;
    const int tid = threadIdx.x;

    __shared__ float sdt[64 * 33]; // [row][k], padded stride 33
    __shared__ float T[64 * 65];   // [c][r]

    for (int idx = tid; idx < 64 * 32; idx += 256) {
        const int r = idx >> 5, k = idx & 31;
        sdt[r * 33 + k] = dbc[(size_t)(r0 + r) * 64 + k];
    }
    __syncthreads();

    const int c = tid & 63;
    const int rgrp = tid >> 6;
    float wv[RK];
#pragma unroll
    for (int k = 0; k < RK / 4; ++k) {
        const float4 t4 = *(const float4*)(dtw + (size_t)(c0 + c) * RK + k * 4);
        wv[4 * k] = t4.x; wv[4 * k + 1] = t4.y; wv[4 * k + 2] = t4.z; wv[4 * k + 3] = t4.w;
    }
    const float bv = dtb[c0 + c];
#pragma unroll
    for (int i = 0; i < 16; ++i) {
        const int r = rgrp + i * 4;
        float acc = bv;
#pragma unroll
        for (int k = 0; k < RK; ++k) acc = fmaf(sdt[r * 33 + k], wv[k], acc);
        T[c * 65 + r] = (acc > 20.f) ? acc : log1pf(expf(acc));
    }
    __syncthreads();
#pragma unroll
    for (int i = 0; i < 16; ++i) {
        const int idx = tid + i * 256;
        const int cc = idx >> 6, r = idx & 63;
        delta_t[(size_t)(c0 + cc) * MR_ROWS + r0 + r] = T[cc * 65 + r];
    }

    // B/C transpose: bct[k][row] = dbc[row][32+k], k in [0,32)
    if (c0 == 0) {
        for (int idx = tid; idx < 32 * 64; idx += 256) {
            const int k = idx >> 6, r = idx & 63;
            bct[(size_t)k * MR_ROWS + r0 + r] = dbc[(size_t)(r0 + r) * 64 + 32 + k];
        }
    }
}

// ---------------------------------------------------------------------------
// Selective scan, chunked 3-phase, channel-major inputs staged in LDS,
// B/C streamed into registers as float4 (contiguous per thread, L2-resident).
// Block = 256 thr = 16 time-chunks x 16 states; one channel per block.
// ---------------------------------------------------------------------------
__global__ __launch_bounds__(256) void scan_kernel(const float* __restrict__ delta_t,
                                                   const float* __restrict__ xc_t,
                                                   const float* __restrict__ zs_t,
                                                   const float* __restrict__ bct,
                                                   const float* __restrict__ Alog,
                                                   const float* __restrict__ Dp,
                                                   bf16* __restrict__ yg) {
    const int b = blockIdx.y;
    const int c = blockIdx.x;
    const int tid = threadIdx.x;
    const int n = tid & 15;
    const int chunk = tid >> 4;
    const size_t rbase = (size_t)b * LL;
    const int t0 = chunk * 64;

    __shared__ float sdel[16 * 68], sxc[16 * 68], szs[16 * 68];
    __shared__ float sP[16][16], sS[16][16], sH[16][16];

    {   // cooperative stage: 1024 floats each, float4 per thread
        const size_t base = (size_t)c * MR_ROWS + rbase;
        const int ch = tid >> 4, tl = (tid & 15) * 4;
        *(float4*)(sdel + ch * 68 + tl) = *(const float4*)(delta_t + base + tid * 4);
        *(float4*)(sxc  + ch * 68 + tl) = *(const float4*)(xc_t  + base + tid * 4);
        *(float4*)(szs  + ch * 68 + tl) = *(const float4*)(zs_t  + base + tid * 4);
    }

    const float a2 = -expf(Alog[(size_t)c * DSN + n]) * 1.44269504f;
    const float dp = Dp[c];
    const float* Bp = bct + (size_t)n * MR_ROWS + rbase + t0;
    const float* Cp = bct + (size_t)(16 + n) * MR_ROWS + rbase + t0;
    __syncthreads();

    // phase 1: local scan, h0=0, track P = prod dA
    float h = 0.f, P = 1.f;
#pragma unroll 4
    for (int tq = 0; tq < 16; ++tq) {
        const float4 b4 = *(const float4*)(Bp + tq * 4);
#pragma unroll
        for (int j = 0; j < 4; ++j) {
            const int t = tq * 4 + j;
            const float d  = sdel[chunk * 68 + t];
            const float xv = sxc[chunk * 68 + t];
            const float bm = (j == 0) ? b4.x : (j == 1) ? b4.y : (j == 2) ? b4.z : b4.w;
            const float dA = exp2f(d * a2);
            h = fmaf(dA, h, d * bm * xv);
            P *= dA;
        }
    }
    sP[chunk][n] = P;
    sS[chunk][n] = h;
    __syncthreads();

    // phase 2: serial combine across chunks (one thread per state)
    if (tid < 16) {
        float hh = 0.f;
#pragma unroll
        for (int j = 0; j < 16; ++j) {
            sH[j][tid] = hh;
            hh = fmaf(sP[j][tid], hh, sS[j][tid]);
        }
    }
    __syncthreads();

    // phase 3: re-scan with correct h_in, emit gated output
    h = sH[chunk][n];
#pragma unroll 4
    for (int tq = 0; tq < 16; ++tq) {
        const float4 b4 = *(const float4*)(Bp + tq * 4);
        const float4 c4 = *(const float4*)(Cp + tq * 4);
#pragma unroll
        for (int j = 0; j < 4; ++j) {
            const int t = tq * 4 + j;
            const float d  = sdel[chunk * 68 + t];
            const float xv = sxc[chunk * 68 + t];
            const float bm = (j == 0) ? b4.x : (j == 1) ? b4.y : (j == 2) ? b4.z : b4.w;
            const float cm = (j == 0) ? c4.x : (j == 1) ? c4.y : (j == 2) ? c4.z : c4.w;
            const float dA = exp2f(d * a2);
            h = fmaf(dA, h, d * bm * xv);
            float part = h * cm;
            part += __shfl_xor(part, 1);
            part += __shfl_xor(part, 2);
            part += __shfl_xor(part, 4);
            part += __shfl_xor(part, 8);
            if (n == 0) {
                yg[(rbase + t0 + t) * DI + c] =
                    __float2bfloat16((part + dp * xv) * szs[chunk * 68 + t]);
            }
        }
    }
}

// ---------------------------------------------------------------------------
// One Mamba layer
// ---------------------------------------------------------------------------
static void run_mamba_layer(hipStream_t stream, float* resid,
                            const float* ln_w, const float* ln_b,
                            const bf16* inw_bf,
                            const float* conv_w, const float* conv_b,
                            const bf16* xpw_bf,
                            const float* dt_w, const float* dt_b,
                            const float* Alog, const float* Dp,
                            const bf16* outw_bf,
                            bf16* ln_bf, float* xz, bf16* xc_bf,
                            float* xc_t, float* zs_t,
                            float* dbc, float* bct, float* delta_t, bf16* yg_bf) {
    ln_kernel<bf16><<<MR_ROWS, 256, 0, stream>>>(resid, ln_w, ln_b, ln_bf);
    // xz = ln_out @ in_w^T : M=2048, N=2048, K=512 (64x64 tiles -> 1024 blocks)
    gemm_bt<64, 64, 64, 0><<<dim3(2 * DI / 64, MR_ROWS / 64), 256, 0, stream>>>(
        ln_bf, DM, inw_bf, DM, xz, 2 * DI, DM, nullptr);
    conv_silu_T<<<dim3(DI / 64, MR_ROWS / 64), 256, 0, stream>>>(
        xz, conv_w, conv_b, xc_bf, xc_t, zs_t);
    // dbc = xc @ xp_w^T : M=2048, N=64, K=1024, split-K x4 -> 256 blocks
    hipMemsetAsync(dbc, 0, (size_t)MR_ROWS * 64 * 4, stream);
    gemm_bt<32, 64, 64, 2><<<dim3(1, MR_ROWS / 32, 4), 256, 0, stream>>>(
        xc_bf, DI, xpw_bf, DI, dbc, 64, DI / 4, nullptr);
    dtproj_T<<<dim3(DI / 64, MR_ROWS / 64), 256, 0, stream>>>(dbc, dt_w, dt_b, delta_t, bct);
    scan_kernel<<<dim3(DI, LB), 256, 0, stream>>>(delta_t, xc_t, zs_t, bct, Alog, Dp, yg_bf);
    // resid += yg @ out_w^T : M=2048, N=512, K=1024 (32x64 -> 512 blocks)
    gemm_bt<32, 64, 64, 3><<<dim3(DM / 64, MR_ROWS / 32), 256, 0, stream>>>(
        yg_bf, DI, outw_bf, DI, resid, DM, DI, nullptr);
}

// ---------------------------------------------------------------------------
extern "C" void kernel_launch(void* const* d_in, const int* in_sizes, int n_in,
                              void* d_out, int out_size, void* d_ws, size_t ws_size,
                              hipStream_t stream) {
    const float* x         = (const float*)d_in[0];
    const float* inp_w     = (const float*)d_in[1];
    const float* inp_b     = (const float*)d_in[2];
    const float* enc_ln_w  = (const float*)d_in[3];
    const float* enc_ln_b  = (const float*)d_in[4];
    const float* enc_in_w  = (const float*)d_in[5];
    const float* enc_conv_w= (const float*)d_in[6];
    const float* enc_conv_b= (const float*)d_in[7];
    const float* enc_xp_w  = (const float*)d_in[8];
    const float* enc_dt_w  = (const float*)d_in[9];
    const float* enc_dt_b  = (const float*)d_in[10];
    const float* enc_Alog  = (const float*)d_in[11];
    const float* enc_D     = (const float*)d_in[12];
    const float* enc_out_w = (const float*)d_in[13];
    const float* fin_ln_w  = (const float*)d_in[14];
    const float* fin_ln_b  = (const float*)d_in[15];
    const float* prd_ln_w  = (const float*)d_in[16];
    const float* prd_ln_b  = (const float*)d_in[17];
    const float* prd_in_w  = (const float*)d_in[18];
    const float* prd_conv_w= (const float*)d_in[19];
    const float* prd_conv_b= (const float*)d_in[20];
    const float* prd_xp_w  = (const float*)d_in[21];
    const float* prd_dt_w  = (const float*)d_in[22];
    const float* prd_dt_b  = (const float*)d_in[23];
    const float* prd_Alog  = (const float*)d_in[24];
    const float* prd_D     = (const float*)d_in[25];
    const float* prd_out_w = (const float*)d_in[26];
    const float* prd_nrm_w = (const float*)d_in[27];
    const float* prd_nrm_b = (const float*)d_in[28];
    const float* prd_proj_w= (const float*)d_in[29];
    const float* prd_proj_b= (const float*)d_in[30];

    char* wp = (char*)d_ws;
    auto carve = [&](size_t elems, size_t esz) {
        void* p = (void*)wp;
        wp += (elems * esz + 255) & ~(size_t)255;
        return p;
    };
    bf16* x_bf     = (bf16*)carve((size_t)MR_ROWS * 128, 2);
    bf16* inpw_bf  = (bf16*)carve((size_t)DM * 128, 2);
    bf16* einw_bf  = (bf16*)carve(4ull * 2 * DI * DM, 2);
    bf16* expw_bf  = (bf16*)carve(4ull * 64 * DI, 2);
    bf16* eoutw_bf = (bf16*)carve(4ull * DM * DI, 2);
    bf16* pinw_bf  = (bf16*)carve(2ull * 2 * DI * DM, 2);
    bf16* pxpw_bf  = (bf16*)carve(2ull * 64 * DI, 2);
    bf16* poutw_bf = (bf16*)carve(2ull * DM * DI, 2);
    bf16* projw_bf = (bf16*)carve((size_t)DM * DM, 2);
    float* hbuf    = (float*)carve((size_t)MR_ROWS * DM, 4);
    float* pbuf    = (float*)carve((size_t)MR_ROWS * DM, 4);
    bf16* ln_bf    = (bf16*)carve((size_t)MR_ROWS * DM, 2);
    float* xz      = (float*)carve((size_t)MR_ROWS * 2 * DI, 4);
    bf16* xc_bf    = (bf16*)carve((size_t)MR_ROWS * DI, 2);
    float* xc_t    = (float*)carve((size_t)MR_ROWS * DI, 4);
    float* zs_t    = (float*)carve((size_t)MR_ROWS * DI, 4);
    float* dbc     = (float*)carve((size_t)MR_ROWS * 64, 4);
    float* bct     = (float*)carve(32ull * MR_ROWS, 4);
    float* delta_t = (float*)carve((size_t)MR_ROWS * DI, 4);
    bf16* yg_bf    = (bf16*)carve((size_t)MR_ROWS * DI, 2);

    // --- weight/input conversion to bf16 (one launch) ---
    ConvArgs ca;
    const float* csrc[9] = {x, inp_w, enc_in_w, enc_xp_w, enc_out_w,
                            prd_in_w, prd_xp_w, prd_out_w, prd_proj_w};
    bf16* cdst[9] = {x_bf, inpw_bf, einw_bf, expw_bf, eoutw_bf,
                     pinw_bf, pxpw_bf, poutw_bf, projw_bf};
    const int cn[9] = {MR_ROWS * 128, DM * 128, 4 * 2 * DI * DM, 4 * 64 * DI, 4 * DM * DI,
                       2 * 2 * DI * DM, 2 * 64 * DI, 2 * DM * DI, DM * DM};
    for (int i = 0; i < 9; ++i) { ca.src[i] = csrc[i]; ca.dst[i] = cdst[i]; ca.n4[i] = cn[i] / 4; }
    convert_bf16_multi<<<dim3(128, 9), 256, 0, stream>>>(ca);

    // --- input projection: h = x @ inp_w^T + inp_b  (M=2048, N=512, K=128) ---
    gemm_bt<32, 64, 64, 1><<<dim3(DM / 64, MR_ROWS / 32), 256, 0, stream>>>(
        x_bf, 128, inpw_bf, 128, hbuf, DM, 128, inp_b);

    // --- encoder layers ---
    for (int i = 0; i < 4; ++i) {
        run_mamba_layer(stream, hbuf,
                        enc_ln_w + (size_t)i * DM, enc_ln_b + (size_t)i * DM,
                        einw_bf + (size_t)i * 2 * DI * DM,
                        enc_conv_w + (size_t)i * DI * 4, enc_conv_b + (size_t)i * DI,
                        expw_bf + (size_t)i * 64 * DI,
                        enc_dt_w + (size_t)i * DI * RK, enc_dt_b + (size_t)i * DI,
                        enc_Alog + (size_t)i * DI * DSN, enc_D + (size_t)i * DI,
                        eoutw_bf + (size_t)i * DM * DI,
                        ln_bf, xz, xc_bf, xc_t, zs_t, dbc, bct, delta_t, yg_bf);
    }

    // --- final encoder LN -> predictor stream ---
    ln_kernel<float><<<MR_ROWS, 256, 0, stream>>>(hbuf, fin_ln_w, fin_ln_b, pbuf);

    // --- predictor layers ---
    for (int i = 0; i < 2; ++i) {
        run_mamba_layer(stream, pbuf,
                        prd_ln_w + (size_t)i * DM, prd_ln_b + (size_t)i * DM,
                        pinw_bf + (size_t)i * 2 * DI * DM,
                        prd_conv_w + (size_t)i * DI * 4, prd_conv_b + (size_t)i * DI,
                        pxpw_bf + (size_t)i * 64 * DI,
                        prd_dt_w + (size_t)i * DI * RK, prd_dt_b + (size_t)i * DI,
                        prd_Alog + (size_t)i * DI * DSN, prd_D + (size_t)i * DI,
                        poutw_bf + (size_t)i * DM * DI,
                        ln_bf, xz, xc_bf, xc_t, zs_t, dbc, bct, delta_t, yg_bf);
    }

    // --- final norm + projection ---
    ln_kernel<bf16><<<MR_ROWS, 256, 0, stream>>>(pbuf, prd_nrm_w, prd_nrm_b, ln_bf);
    gemm_bt<32, 64, 64, 1><<<dim3(DM / 64, MR_ROWS / 32), 256, 0, stream>>>(
        ln_bf, DM, projw_bf, DM, (float*)d_out, DM, DM, prd_proj_b);

    (void)in_sizes; (void)n_in; (void)out_size; (void)ws_size;
}

// Round 5
// 755.557 us; speedup vs baseline: 1.2027x; 1.2027x over previous
//
#include <hip/hip_runtime.h>
#include <hip/hip_bf16.h>

using bf16 = __hip_bfloat16;
typedef __attribute__((ext_vector_type(8))) short short8;
typedef __attribute__((ext_vector_type(4))) float f32x4;
typedef __attribute__((ext_vector_type(4))) unsigned int uint4v;

// Problem constants
static constexpr int LB = 2;           // batch
static constexpr int LL = 1024;        // seq len
static constexpr int DM = 512;         // d_model
static constexpr int DI = 1024;        // d_inner
static constexpr int DSN = 16;         // d_state
static constexpr int RK = 32;          // dt_rank
static constexpr int MR_ROWS = LB * LL; // 2048 rows

static constexpr int NCHUNK = 64;      // time chunks per sequence
static constexpr int CH = LL / NCHUNK; // 16 steps per chunk

// ---------------------------------------------------------------------------
// fp32 -> bf16 conversion, multi-segment in one launch
// ---------------------------------------------------------------------------
struct ConvArgs {
    const float* src[9];
    bf16*        dst[9];
    int          n4[9];
};

__global__ __launch_bounds__(256) void convert_bf16_multi(ConvArgs a) {
    const int s = blockIdx.y;
    const float4* __restrict__ src = (const float4*)a.src[s];
    bf16* __restrict__ dst = a.dst[s];
    const int n4 = a.n4[s];
    for (int i = blockIdx.x * 256 + threadIdx.x; i < n4; i += gridDim.x * 256) {
        float4 v = src[i];
        bf16 t[4] = {__float2bfloat16(v.x), __float2bfloat16(v.y),
                     __float2bfloat16(v.z), __float2bfloat16(v.w)};
        *(uint2*)(dst + (size_t)i * 4) = *(uint2*)t;
    }
}

// ---------------------------------------------------------------------------
// LayerNorm over last dim (512). One block (256 thr) per row, 2 elems/thread.
// ---------------------------------------------------------------------------
__device__ __forceinline__ void ln_store(float* outrow, int tid, float a, float b) {
    ((float2*)outrow)[tid] = make_float2(a, b);
}
__device__ __forceinline__ void ln_store(bf16* outrow, int tid, float a, float b) {
    __hip_bfloat162 h;
    h.x = __float2bfloat16(a);
    h.y = __float2bfloat16(b);
    ((__hip_bfloat162*)outrow)[tid] = h;
}

template <typename T>
__global__ __launch_bounds__(256) void ln_kernel(const float* __restrict__ x,
                                                 const float* __restrict__ w,
                                                 const float* __restrict__ b,
                                                 T* __restrict__ out) {
    const int row = blockIdx.x;
    const int tid = threadIdx.x;
    const int wid = tid >> 6, lane = tid & 63;
    __shared__ float red[8];

    const float2 v = ((const float2*)(x + (size_t)row * DM))[tid];
    float s = v.x + v.y;
#pragma unroll
    for (int m = 1; m < 64; m <<= 1) s += __shfl_xor(s, m);
    if (lane == 0) red[wid] = s;
    __syncthreads();
    const float mean = (red[0] + red[1] + red[2] + red[3]) * (1.f / DM);
    const float d0 = v.x - mean, d1 = v.y - mean;
    float s2 = d0 * d0 + d1 * d1;
#pragma unroll
    for (int m = 1; m < 64; m <<= 1) s2 += __shfl_xor(s2, m);
    if (lane == 0) red[4 + wid] = s2;
    __syncthreads();
    const float var = (red[4] + red[5] + red[6] + red[7]) * (1.f / DM);
    const float rs = rsqrtf(var + 1e-5f);
    const float2 wv = ((const float2*)w)[tid];
    const float2 bv = ((const float2*)b)[tid];
    ln_store(out + (size_t)row * DM, tid, d0 * rs * wv.x + bv.x, d1 * rs * wv.y + bv.y);
}

// ---------------------------------------------------------------------------
// GEMM: C[M,N] = A[M,K] * B[N,K]^T  (A,B bf16 row-major K-contiguous, C fp32)
// EPI: 0 = none, 1 = +bias[col], 2 = atomicAdd (split-K over blockIdx.z,
//      K arg = per-chunk K), 3 = += existing C (residual)
// LDS XOR-swizzle (T2): row stride is 128B (BK=64); byte ^= (row&7)<<4 on both
// the staging write and the fragment read.
// ---------------------------------------------------------------------------
template <int BM, int BN, int BK, int EPI>
__global__ __launch_bounds__(256) void gemm_bt(const bf16* __restrict__ A, int lda,
                                               const bf16* __restrict__ B, int ldb,
                                               float* __restrict__ C, int ldc,
                                               int K, const float* __restrict__ bias) {
    static_assert(BK == 64, "swizzle assumes 128B LDS row stride");
    constexpr int MR = (BM / 2) / 16;
    constexpr int NR = (BN / 2) / 16;
    __shared__ __align__(16) bf16 sA[BM * BK];
    __shared__ __align__(16) bf16 sB[BN * BK];

    const int tid = threadIdx.x;
    const int lane = tid & 63, wid = tid >> 6;
    const int wr = wid >> 1, wc = wid & 1;
    const int m0 = blockIdx.y * BM, n0 = blockIdx.x * BN;
    const int kbase = (EPI == 2) ? blockIdx.z * K : 0;

    f32x4 acc[MR][NR] = {};

    constexpr int A_LD = BM * BK * 2 / (256 * 16);
    constexpr int B_LD = BN * BK * 2 / (256 * 16);
    static_assert(A_LD >= 1 && B_LD >= 1, "tile too small");

    for (int k0 = kbase; k0 < kbase + K; k0 += BK) {
#pragma unroll
        for (int i = 0; i < A_LD; ++i) {
            const int byte = (tid + i * 256) * 16;
            const int row = byte / (BK * 2), colb = byte % (BK * 2);
            const int sw = colb ^ ((row & 7) << 4);
            *(uint4v*)((char*)sA + row * (BK * 2) + sw) =
                *(const uint4v*)((const char*)A + ((size_t)(m0 + row) * lda + k0) * 2 + colb);
        }
#pragma unroll
        for (int i = 0; i < B_LD; ++i) {
            const int byte = (tid + i * 256) * 16;
            const int row = byte / (BK * 2), colb = byte % (BK * 2);
            const int sw = colb ^ ((row & 7) << 4);
            *(uint4v*)((char*)sB + row * (BK * 2) + sw) =
                *(const uint4v*)((const char*)B + ((size_t)(n0 + row) * ldb + k0) * 2 + colb);
        }
        __syncthreads();
#pragma unroll
        for (int kk = 0; kk < BK; kk += 32) {
            const int kb2 = (kk + (lane >> 4) * 8) * 2; // byte col, 16B aligned
            short8 af[MR], bfr[NR];
#pragma unroll
            for (int m = 0; m < MR; ++m) {
                const int r = wr * (BM / 2) + m * 16 + (lane & 15);
                af[m] = *(const short8*)((const char*)sA + r * (BK * 2) + (kb2 ^ ((r & 7) << 4)));
            }
#pragma unroll
            for (int n = 0; n < NR; ++n) {
                const int r = wc * (BN / 2) + n * 16 + (lane & 15);
                bfr[n] = *(const short8*)((const char*)sB + r * (BK * 2) + (kb2 ^ ((r & 7) << 4)));
            }
#pragma unroll
            for (int m = 0; m < MR; ++m) {
#pragma unroll
                for (int n = 0; n < NR; ++n) {
                    acc[m][n] = __builtin_amdgcn_mfma_f32_16x16x32_bf16(af[m], bfr[n], acc[m][n], 0, 0, 0);
                }
            }
        }
        __syncthreads();
    }

#pragma unroll
    for (int m = 0; m < MR; ++m) {
#pragma unroll
        for (int n = 0; n < NR; ++n) {
            const int col = n0 + wc * (BN / 2) + n * 16 + (lane & 15);
            const float bv = (EPI == 1) ? bias[col] : 0.f;
#pragma unroll
            for (int j = 0; j < 4; ++j) {
                const int row = m0 + wr * (BM / 2) + m * 16 + (lane >> 4) * 4 + j;
                float v = acc[m][n][j] + bv;
                float* p = C + (size_t)row * ldc + col;
                if (EPI == 2) {
                    atomicAdd(p, v);
                } else {
                    if (EPI == 3) v += *p;
                    *p = v;
                }
            }
        }
    }
}

// ---------------------------------------------------------------------------
// Causal depthwise conv (K=4) + SiLU. xi = xz[:, 0:DI]. Writes fp32 + bf16,
// both row-major (the scan reads row-major with channel in the lane dim).
// ---------------------------------------------------------------------------
__global__ __launch_bounds__(256) void conv_silu_kernel(const float* __restrict__ xz,
                                                        const float* __restrict__ cw,
                                                        const float* __restrict__ cb,
                                                        float* __restrict__ xc,
                                                        bf16* __restrict__ xc_bf) {
    const int idx = blockIdx.x * 256 + threadIdx.x; // over 2048*1024
    const int c = idx & (DI - 1);
    const int r = idx >> 10;
    const int l = r & (LL - 1);
    const float* xi = xz + (size_t)r * (2 * DI) + c;
    const float4 w = *(const float4*)(cw + (size_t)c * 4);
    float acc = cb[c] + w.w * xi[0];
    if (l >= 1) acc += w.z * xi[-(2 * DI)];
    if (l >= 2) acc += w.y * xi[-(4 * DI)];
    if (l >= 3) acc += w.x * xi[-(6 * DI)];
    const float s = acc / (1.f + expf(-acc)); // silu
    xc[idx] = s;
    xc_bf[idx] = __float2bfloat16(s);
}

// ---------------------------------------------------------------------------
// delta = softplus(dt @ dt_w^T + dt_b), row-major output.
// grid (2048 rows, 4 col-chunks of 256)
// ---------------------------------------------------------------------------
__global__ __launch_bounds__(256) void dtproj_kernel(const float* __restrict__ dbc,
                                                     const float* __restrict__ dtw,
                                                     const float* __restrict__ dtb,
                                                     float* __restrict__ delta) {
    __shared__ float sdt[RK];
    const int r = blockIdx.x;
    if (threadIdx.x < RK) sdt[threadIdx.x] = dbc[(size_t)r * 64 + threadIdx.x];
    __syncthreads();
    const int c = blockIdx.y * 256 + threadIdx.x;
    const float4* w4 = (const float4*)(dtw + (size_t)c * RK);
    float acc = dtb[c];
#pragma unroll
    for (int k = 0; k < RK / 4; ++k) {
        const float4 wv = w4[k];
        acc = fmaf(sdt[4 * k + 0], wv.x, acc);
        acc = fmaf(sdt[4 * k + 1], wv.y, acc);
        acc = fmaf(sdt[4 * k + 2], wv.z, acc);
        acc = fmaf(sdt[4 * k + 3], wv.w, acc);
    }
    delta[(size_t)r * DI + c] = (acc > 20.f) ? acc : log1pf(expf(acc));
}

// ---------------------------------------------------------------------------
// Selective scan, 3-kernel chunked form. Channel in the LANE dimension:
//   thread = (b, c, chunk); all 16 states live in the thread's registers.
//   delta/xc reads: 64 lanes = 64 consecutive channels -> coalesced 256B.
//   B/C reads: wave-uniform address -> broadcast, 1 line per load.
//   No shuffles; y-reduction is in-thread with 4 partial accumulators.
// K1: per-chunk P = prod(dA), S = local h (from h0=0) -> psum/ssum.
// K2: serial combine over chunks, writes h_in in-place over psum.
// K3: re-scan from h_in, y = sum_n h*C, gate with silu(z), store bf16.
// psum/ssum layout: [b][chunk][n][c] (stride DI in c -> lane-coalesced).
// ---------------------------------------------------------------------------
__global__ __launch_bounds__(256) void scan_part1(const float* __restrict__ delta,
                                                  const float* __restrict__ xc,
                                                  const float* __restrict__ dbc,
                                                  const float* __restrict__ Alog,
                                                  float* __restrict__ psum,
                                                  float* __restrict__ ssum) {
    const int lane = threadIdx.x & 63;
    const int wsub = threadIdx.x >> 6;
    const int c = blockIdx.x * 64 + lane;
    const int chunk = blockIdx.y * 4 + wsub;
    const int b = blockIdx.z;
    const int r0 = b * LL + chunk * CH;

    float a2[DSN];
#pragma unroll
    for (int q = 0; q < 4; ++q) {
        const float4 al = *(const float4*)(Alog + (size_t)c * DSN + q * 4);
        a2[q * 4 + 0] = -expf(al.x) * 1.44269504f;
        a2[q * 4 + 1] = -expf(al.y) * 1.44269504f;
        a2[q * 4 + 2] = -expf(al.z) * 1.44269504f;
        a2[q * 4 + 3] = -expf(al.w) * 1.44269504f;
    }

    float h[DSN], P[DSN];
#pragma unroll
    for (int n = 0; n < DSN; ++n) { h[n] = 0.f; P[n] = 1.f; }

    for (int t = 0; t < CH; ++t) {
        const size_t r = r0 + t;
        const float d  = delta[r * DI + c];
        const float xv = xc[r * DI + c];
        const float dxv = d * xv;
        float Bv[DSN];
#pragma unroll
        for (int q = 0; q < 4; ++q)
            *(float4*)&Bv[q * 4] = *(const float4*)(dbc + r * 64 + 32 + q * 4);
#pragma unroll
        for (int n = 0; n < DSN; ++n) {
            const float dA = exp2f(d * a2[n]);
            h[n] = fmaf(dA, h[n], dxv * Bv[n]);
            P[n] *= dA;
        }
    }

    const size_t obase = ((size_t)(b * NCHUNK + chunk) * DSN) * DI + c;
#pragma unroll
    for (int n = 0; n < DSN; ++n) {
        psum[obase + (size_t)n * DI] = P[n];
        ssum[obase + (size_t)n * DI] = h[n];
    }
}

__global__ __launch_bounds__(256) void scan_combine(float* __restrict__ psum,
                                                    const float* __restrict__ ssum) {
    const int lane = threadIdx.x & 63;
    const int idx = blockIdx.y * 4 + (threadIdx.x >> 6); // [0,32): b*16+n
    const int b = idx >> 4, n = idx & 15;
    const int c = blockIdx.x * 64 + lane;
    const size_t base = ((size_t)(b * NCHUNK) * DSN + n) * DI + c;
    const size_t stride = (size_t)DSN * DI; // chunk stride

    float h = 0.f;
    for (int j0 = 0; j0 < NCHUNK; j0 += 8) {
        float Pv[8], Sv[8];
#pragma unroll
        for (int u = 0; u < 8; ++u) {
            Pv[u] = psum[base + (j0 + u) * stride];
            Sv[u] = ssum[base + (j0 + u) * stride];
        }
#pragma unroll
        for (int u = 0; u < 8; ++u) {
            psum[base + (j0 + u) * stride] = h; // h_in for chunk j0+u
            h = fmaf(Pv[u], h, Sv[u]);
        }
    }
}

__global__ __launch_bounds__(256) void scan_part3(const float* __restrict__ delta,
                                                  const float* __restrict__ xc,
                                                  const float* __restrict__ xz,
                                                  const float* __restrict__ dbc,
                                                  const float* __restrict__ Alog,
                                                  const float* __restrict__ Dp,
                                                  const float* __restrict__ hin,
                                                  bf16* __restrict__ yg) {
    const int lane = threadIdx.x & 63;
    const int wsub = threadIdx.x >> 6;
    const int c = blockIdx.x * 64 + lane;
    const int chunk = blockIdx.y * 4 + wsub;
    const int b = blockIdx.z;
    const int r0 = b * LL + chunk * CH;

    float a2[DSN];
#pragma unroll
    for (int q = 0; q < 4; ++q) {
        const float4 al = *(const float4*)(Alog + (size_t)c * DSN + q * 4);
        a2[q * 4 + 0] = -expf(al.x) * 1.44269504f;
        a2[q * 4 + 1] = -expf(al.y) * 1.44269504f;
        a2[q * 4 + 2] = -expf(al.z) * 1.44269504f;
        a2[q * 4 + 3] = -expf(al.w) * 1.44269504f;
    }
    const float dp = Dp[c];

    float h[DSN];
    const size_t hbase = ((size_t)(b * NCHUNK + chunk) * DSN) * DI + c;
#pragma unroll
    for (int n = 0; n < DSN; ++n) h[n] = hin[hbase + (size_t)n * DI];

    for (int t = 0; t < CH; ++t) {
        const size_t r = r0 + t;
        const float d  = delta[r * DI + c];
        const float xv = xc[r * DI + c];
        const float zv = xz[r * (2 * DI) + DI + c];
        const float dxv = d * xv;
        float Bv[DSN], Cv[DSN];
#pragma unroll
        for (int q = 0; q < 4; ++q) {
            *(float4*)&Bv[q * 4] = *(const float4*)(dbc + r * 64 + 32 + q * 4);
            *(float4*)&Cv[q * 4] = *(const float4*)(dbc + r * 64 + 48 + q * 4);
        }
        float y0 = 0.f, y1 = 0.f, y2 = 0.f, y3 = 0.f;
#pragma unroll
        for (int q = 0; q < 4; ++q) {
            {
                const float dA = exp2f(d * a2[q * 4 + 0]);
                h[q * 4 + 0] = fmaf(dA, h[q * 4 + 0], dxv * Bv[q * 4 + 0]);
                y0 = fmaf(h[q * 4 + 0], Cv[q * 4 + 0], y0);
            }
            {
                const float dA = exp2f(d * a2[q * 4 + 1]);
                h[q * 4 + 1] = fmaf(dA, h[q * 4 + 1], dxv * Bv[q * 4 + 1]);
                y1 = fmaf(h[q * 4 + 1], Cv[q * 4 + 1], y1);
            }
            {
                const float dA = exp2f(d * a2[q * 4 + 2]);
                h[q * 4 + 2] = fmaf(dA, h[q * 4 + 2], dxv * Bv[q * 4 + 2]);
                y2 = fmaf(h[q * 4 + 2], Cv[q * 4 + 2], y2);
            }
            {
                const float dA = exp2f(d * a2[q * 4 + 3]);
                h[q * 4 + 3] = fmaf(dA, h[q * 4 + 3], dxv * Bv[q * 4 + 3]);
                y3 = fmaf(h[q * 4 + 3], Cv[q * 4 + 3], y3);
            }
        }
        const float y = (y0 + y1) + (y2 + y3);
        const float zs = zv / (1.f + expf(-zv));
        yg[r * DI + c] = __float2bfloat16((y + dp * xv) * zs);
    }
}

// ---------------------------------------------------------------------------
// One Mamba layer
// ---------------------------------------------------------------------------
static void run_mamba_layer(hipStream_t stream, float* resid,
                            const float* ln_w, const float* ln_b,
                            const bf16* inw_bf,
                            const float* conv_w, const float* conv_b,
                            const bf16* xpw_bf,
                            const float* dt_w, const float* dt_b,
                            const float* Alog, const float* Dp,
                            const bf16* outw_bf,
                            bf16* ln_bf, float* xz, float* xc, bf16* xc_bf,
                            float* dbc, float* delta,
                            float* psum, float* ssum, bf16* yg_bf) {
    ln_kernel<bf16><<<MR_ROWS, 256, 0, stream>>>(resid, ln_w, ln_b, ln_bf);
    // xz = ln_out @ in_w^T : M=2048, N=2048, K=512 (64x64 tiles -> 1024 blocks)
    gemm_bt<64, 64, 64, 0><<<dim3(2 * DI / 64, MR_ROWS / 64), 256, 0, stream>>>(
        ln_bf, DM, inw_bf, DM, xz, 2 * DI, DM, nullptr);
    conv_silu_kernel<<<MR_ROWS * DI / 256, 256, 0, stream>>>(xz, conv_w, conv_b, xc, xc_bf);
    // dbc = xc @ xp_w^T : M=2048, N=64, K=1024, split-K x4 -> 256 blocks
    hipMemsetAsync(dbc, 0, (size_t)MR_ROWS * 64 * 4, stream);
    gemm_bt<32, 64, 64, 2><<<dim3(1, MR_ROWS / 32, 4), 256, 0, stream>>>(
        xc_bf, DI, xpw_bf, DI, dbc, 64, DI / 4, nullptr);
    dtproj_kernel<<<dim3(MR_ROWS, DI / 256), 256, 0, stream>>>(dbc, dt_w, dt_b, delta);
    // 3-kernel chunked scan
    scan_part1<<<dim3(DI / 64, NCHUNK / 4, LB), 256, 0, stream>>>(
        delta, xc, dbc, Alog, psum, ssum);
    scan_combine<<<dim3(DI / 64, (LB * DSN) / 4), 256, 0, stream>>>(psum, ssum);
    scan_part3<<<dim3(DI / 64, NCHUNK / 4, LB), 256, 0, stream>>>(
        delta, xc, xz, dbc, Alog, Dp, psum, yg_bf);
    // resid += yg @ out_w^T : M=2048, N=512, K=1024 (32x64 -> 512 blocks)
    gemm_bt<32, 64, 64, 3><<<dim3(DM / 64, MR_ROWS / 32), 256, 0, stream>>>(
        yg_bf, DI, outw_bf, DI, resid, DM, DI, nullptr);
}

// ---------------------------------------------------------------------------
extern "C" void kernel_launch(void* const* d_in, const int* in_sizes, int n_in,
                              void* d_out, int out_size, void* d_ws, size_t ws_size,
                              hipStream_t stream) {
    const float* x         = (const float*)d_in[0];
    const float* inp_w     = (const float*)d_in[1];
    const float* inp_b     = (const float*)d_in[2];
    const float* enc_ln_w  = (const float*)d_in[3];
    const float* enc_ln_b  = (const float*)d_in[4];
    const float* enc_in_w  = (const float*)d_in[5];
    const float* enc_conv_w= (const float*)d_in[6];
    const float* enc_conv_b= (const float*)d_in[7];
    const float* enc_xp_w  = (const float*)d_in[8];
    const float* enc_dt_w  = (const float*)d_in[9];
    const float* enc_dt_b  = (const float*)d_in[10];
    const float* enc_Alog  = (const float*)d_in[11];
    const float* enc_D     = (const float*)d_in[12];
    const float* enc_out_w = (const float*)d_in[13];
    const float* fin_ln_w  = (const float*)d_in[14];
    const float* fin_ln_b  = (const float*)d_in[15];
    const float* prd_ln_w  = (const float*)d_in[16];
    const float* prd_ln_b  = (const float*)d_in[17];
    const float* prd_in_w  = (const float*)d_in[18];
    const float* prd_conv_w= (const float*)d_in[19];
    const float* prd_conv_b= (const float*)d_in[20];
    const float* prd_xp_w  = (const float*)d_in[21];
    const float* prd_dt_w  = (const float*)d_in[22];
    const float* prd_dt_b  = (const float*)d_in[23];
    const float* prd_Alog  = (const float*)d_in[24];
    const float* prd_D     = (const float*)d_in[25];
    const float* prd_out_w = (const float*)d_in[26];
    const float* prd_nrm_w = (const float*)d_in[27];
    const float* prd_nrm_b = (const float*)d_in[28];
    const float* prd_proj_w= (const float*)d_in[29];
    const float* prd_proj_b= (const float*)d_in[30];

    char* wp = (char*)d_ws;
    auto carve = [&](size_t elems, size_t esz) {
        void* p = (void*)wp;
        wp += (elems * esz + 255) & ~(size_t)255;
        return p;
    };
    bf16* x_bf     = (bf16*)carve((size_t)MR_ROWS * 128, 2);
    bf16* inpw_bf  = (bf16*)carve((size_t)DM * 128, 2);
    bf16* einw_bf  = (bf16*)carve(4ull * 2 * DI * DM, 2);
    bf16* expw_bf  = (bf16*)carve(4ull * 64 * DI, 2);
    bf16* eoutw_bf = (bf16*)carve(4ull * DM * DI, 2);
    bf16* pinw_bf  = (bf16*)carve(2ull * 2 * DI * DM, 2);
    bf16* pxpw_bf  = (bf16*)carve(2ull * 64 * DI, 2);
    bf16* poutw_bf = (bf16*)carve(2ull * DM * DI, 2);
    bf16* projw_bf = (bf16*)carve((size_t)DM * DM, 2);
    float* hbuf    = (float*)carve((size_t)MR_ROWS * DM, 4);
    float* pbuf    = (float*)carve((size_t)MR_ROWS * DM, 4);
    bf16* ln_bf    = (bf16*)carve((size_t)MR_ROWS * DM, 2);
    float* xz      = (float*)carve((size_t)MR_ROWS * 2 * DI, 4);
    float* xc      = (float*)carve((size_t)MR_ROWS * DI, 4);
    bf16* xc_bf    = (bf16*)carve((size_t)MR_ROWS * DI, 2);
    float* dbc     = (float*)carve((size_t)MR_ROWS * 64, 4);
    float* delta   = (float*)carve((size_t)MR_ROWS * DI, 4);
    float* psum    = (float*)carve((size_t)LB * NCHUNK * DSN * DI, 4);
    float* ssum    = (float*)carve((size_t)LB * NCHUNK * DSN * DI, 4);
    bf16* yg_bf    = (bf16*)carve((size_t)MR_ROWS * DI, 2);

    // --- weight/input conversion to bf16 (one launch) ---
    ConvArgs ca;
    const float* csrc[9] = {x, inp_w, enc_in_w, enc_xp_w, enc_out_w,
                            prd_in_w, prd_xp_w, prd_out_w, prd_proj_w};
    bf16* cdst[9] = {x_bf, inpw_bf, einw_bf, expw_bf, eoutw_bf,
                     pinw_bf, pxpw_bf, poutw_bf, projw_bf};
    const int cn[9] = {MR_ROWS * 128, DM * 128, 4 * 2 * DI * DM, 4 * 64 * DI, 4 * DM * DI,
                       2 * 2 * DI * DM, 2 * 64 * DI, 2 * DM * DI, DM * DM};
    for (int i = 0; i < 9; ++i) { ca.src[i] = csrc[i]; ca.dst[i] = cdst[i]; ca.n4[i] = cn[i] / 4; }
    convert_bf16_multi<<<dim3(128, 9), 256, 0, stream>>>(ca);

    // --- input projection: h = x @ inp_w^T + inp_b  (M=2048, N=512, K=128) ---
    gemm_bt<32, 64, 64, 1><<<dim3(DM / 64, MR_ROWS / 32), 256, 0, stream>>>(
        x_bf, 128, inpw_bf, 128, hbuf, DM, 128, inp_b);

    // --- encoder layers ---
    for (int i = 0; i < 4; ++i) {
        run_mamba_layer(stream, hbuf,
                        enc_ln_w + (size_t)i * DM, enc_ln_b + (size_t)i * DM,
                        einw_bf + (size_t)i * 2 * DI * DM,
                        enc_conv_w + (size_t)i * DI * 4, enc_conv_b + (size_t)i * DI,
                        expw_bf + (size_t)i * 64 * DI,
                        enc_dt_w + (size_t)i * DI * RK, enc_dt_b + (size_t)i * DI,
                        enc_Alog + (size_t)i * DI * DSN, enc_D + (size_t)i * DI,
                        eoutw_bf + (size_t)i * DM * DI,
                        ln_bf, xz, xc, xc_bf, dbc, delta, psum, ssum, yg_bf);
    }

    // --- final encoder LN -> predictor stream ---
    ln_kernel<float><<<MR_ROWS, 256, 0, stream>>>(hbuf, fin_ln_w, fin_ln_b, pbuf);

    // --- predictor layers ---
    for (int i = 0; i < 2; ++i) {
        run_mamba_layer(stream, pbuf,
                        prd_ln_w + (size_t)i * DM, prd_ln_b + (size_t)i * DM,
                        pinw_bf + (size_t)i * 2 * DI * DM,
                        prd_conv_w + (size_t)i * DI * 4, prd_conv_b + (size_t)i * DI,
                        pxpw_bf + (size_t)i * 64 * DI,
                        prd_dt_w + (size_t)i * DI * RK, prd_dt_b + (size_t)i * DI,
                        prd_Alog + (size_t)i * DI * DSN, prd_D + (size_t)i * DI,
                        poutw_bf + (size_t)i * DM * DI,
                        ln_bf, xz, xc, xc_bf, dbc, delta, psum, ssum, yg_bf);
    }

    // --- final norm + projection ---
    ln_kernel<bf16><<<MR_ROWS, 256, 0, stream>>>(pbuf, prd_nrm_w, prd_nrm_b, ln_bf);
    gemm_bt<32, 64, 64, 1><<<dim3(DM / 64, MR_ROWS / 32), 256, 0, stream>>>(
        ln_bf, DM, projw_bf, DM, (float*)d_out, DM, DM, prd_proj_b);

    (void)in_sizes; (void)n_in; (void)out_size; (void)ws_size;
}

// Round 6
// 652.329 us; speedup vs baseline: 1.3930x; 1.1582x over previous
//
#include <hip/hip_runtime.h>
#include <hip/hip_bf16.h>

using bf16 = __hip_bfloat16;
typedef __attribute__((ext_vector_type(8))) short short8;
typedef __attribute__((ext_vector_type(4))) float f32x4;

// Problem constants
static constexpr int LB = 2;           // batch
static constexpr int LL = 1024;        // seq len
static constexpr int DM = 512;         // d_model
static constexpr int DI = 1024;        // d_inner
static constexpr int DSN = 16;         // d_state
static constexpr int RK = 32;          // dt_rank
static constexpr int MR_ROWS = LB * LL; // 2048 rows

static constexpr int NCHUNK = 64;      // time chunks per sequence
static constexpr int CH = LL / NCHUNK; // 16 steps per chunk

// ---------------------------------------------------------------------------
// async global->LDS, 16B per lane. LDS dest is wave-uniform base + lane*16.
// ---------------------------------------------------------------------------
__device__ __forceinline__ void gload16(const void* g, void* l) {
    __builtin_amdgcn_global_load_lds(
        (__attribute__((address_space(1))) void*)(g),
        (__attribute__((address_space(3))) void*)(l), 16, 0, 0);
}

// ---------------------------------------------------------------------------
// fp32 -> bf16 conversion, multi-segment in one launch
// ---------------------------------------------------------------------------
struct ConvArgs {
    const float* src[9];
    bf16*        dst[9];
    int          n4[9];
};

__global__ __launch_bounds__(256) void convert_bf16_multi(ConvArgs a) {
    const int s = blockIdx.y;
    const float4* __restrict__ src = (const float4*)a.src[s];
    bf16* __restrict__ dst = a.dst[s];
    const int n4 = a.n4[s];
    for (int i = blockIdx.x * 256 + threadIdx.x; i < n4; i += gridDim.x * 256) {
        float4 v = src[i];
        bf16 t[4] = {__float2bfloat16(v.x), __float2bfloat16(v.y),
                     __float2bfloat16(v.z), __float2bfloat16(v.w)};
        *(uint2*)(dst + (size_t)i * 4) = *(uint2*)t;
    }
}

// ---------------------------------------------------------------------------
// dtw transpose: out[layer][k][c] = in[layer][c][k]  (fp32, one-time, small)
// ---------------------------------------------------------------------------
__global__ __launch_bounds__(256) void transpose_dtw(const float* __restrict__ enc_dtw,
                                                     const float* __restrict__ prd_dtw,
                                                     float* __restrict__ out) {
    const int layer = blockIdx.y;
    const float* src = (layer < 4) ? enc_dtw + (size_t)layer * DI * RK
                                   : prd_dtw + (size_t)(layer - 4) * DI * RK;
    float* dst = out + (size_t)layer * RK * DI;
    const int idx = blockIdx.x * 256 + threadIdx.x; // over RK*DI
    const int k = idx >> 10, c = idx & (DI - 1);
    dst[idx] = src[(size_t)c * RK + k];
}

// ---------------------------------------------------------------------------
// LayerNorm over last dim (512). One block (256 thr) per row, 2 elems/thread.
// ---------------------------------------------------------------------------
__device__ __forceinline__ void ln_store(float* outrow, int tid, float a, float b) {
    ((float2*)outrow)[tid] = make_float2(a, b);
}
__device__ __forceinline__ void ln_store(bf16* outrow, int tid, float a, float b) {
    __hip_bfloat162 h;
    h.x = __float2bfloat16(a);
    h.y = __float2bfloat16(b);
    ((__hip_bfloat162*)outrow)[tid] = h;
}

template <typename T>
__global__ __launch_bounds__(256) void ln_kernel(const float* __restrict__ x,
                                                 const float* __restrict__ w,
                                                 const float* __restrict__ b,
                                                 T* __restrict__ out) {
    const int row = blockIdx.x;
    const int tid = threadIdx.x;
    const int wid = tid >> 6, lane = tid & 63;
    __shared__ float red[8];

    const float2 v = ((const float2*)(x + (size_t)row * DM))[tid];
    float s = v.x + v.y;
#pragma unroll
    for (int m = 1; m < 64; m <<= 1) s += __shfl_xor(s, m);
    if (lane == 0) red[wid] = s;
    __syncthreads();
    const float mean = (red[0] + red[1] + red[2] + red[3]) * (1.f / DM);
    const float d0 = v.x - mean, d1 = v.y - mean;
    float s2 = d0 * d0 + d1 * d1;
#pragma unroll
    for (int m = 1; m < 64; m <<= 1) s2 += __shfl_xor(s2, m);
    if (lane == 0) red[4 + wid] = s2;
    __syncthreads();
    const float var = (red[4] + red[5] + red[6] + red[7]) * (1.f / DM);
    const float rs = rsqrtf(var + 1e-5f);
    const float2 wv = ((const float2*)w)[tid];
    const float2 bv = ((const float2*)b)[tid];
    ln_store(out + (size_t)row * DM, tid, d0 * rs * wv.x + bv.x, d1 * rs * wv.y + bv.y);
}

// ---------------------------------------------------------------------------
// GEMM: C[M,N] = A[M,K] * B[N,K]^T  (A,B bf16 row-major K-contiguous, C fp32)
// EPI: 0 = none, 1 = +bias[col], 2 = atomicAdd (split-K over blockIdx.z,
//      K arg = per-chunk K), 3 = += existing C (residual)
// Staging via global_load_lds(16B): linear LDS dest, PRE-SWIZZLED global
// source (lane l fetches 16B-block (l&7)^(l>>3) of row l>>3), so the
// swizzled ds_read (byte ^ (row&7)<<4) sees the right data (rule #21).
// ---------------------------------------------------------------------------
template <int BM, int BN, int BK, int EPI>
__global__ __launch_bounds__(256) void gemm_bt(const bf16* __restrict__ A, int lda,
                                               const bf16* __restrict__ B, int ldb,
                                               float* __restrict__ C, int ldc,
                                               int K, const float* __restrict__ bias) {
    static_assert(BK == 64, "layout assumes 128B LDS row");
    static_assert(BM % 32 == 0 && BN % 32 == 0, "wave staging granularity");
    constexpr int MR = (BM / 2) / 16;
    constexpr int NR = (BN / 2) / 16;
    __shared__ __align__(16) char sA[BM * 128];
    __shared__ __align__(16) char sB[BN * 128];

    const int tid = threadIdx.x;
    const int lane = tid & 63, wid = tid >> 6;
    const int wr = wid >> 1, wc = wid & 1;
    const int m0 = blockIdx.y * BM, n0 = blockIdx.x * BN;
    const int kbase = (EPI == 2) ? blockIdx.z * K : 0;

    f32x4 acc[MR][NR] = {};

    // per-lane staging source (pre-swizzled)
    const int lrow = lane >> 3;               // 0..7
    const int lcol = (lane & 7) ^ lrow;       // swizzled 16B block
    const size_t lda2 = (size_t)lda * 2, ldb2 = (size_t)ldb * 2;
    const char* Ab = (const char*)A + (size_t)(m0 + wid * (BM / 4) + lrow) * lda2
                     + lcol * 16 + (size_t)kbase * 2;
    const char* Bb = (const char*)B + (size_t)(n0 + wid * (BN / 4) + lrow) * ldb2
                     + lcol * 16 + (size_t)kbase * 2;
    char* sAw = sA + wid * (BM / 4) * 128;
    char* sBw = sB + wid * (BN / 4) * 128;

    for (int k0 = 0; k0 < K; k0 += BK) {
#pragma unroll
        for (int i = 0; i < BM / 32; ++i)
            gload16(Ab + (size_t)i * 8 * lda2 + (size_t)k0 * 2, sAw + i * 1024);
#pragma unroll
        for (int i = 0; i < BN / 32; ++i)
            gload16(Bb + (size_t)i * 8 * ldb2 + (size_t)k0 * 2, sBw + i * 1024);
        __syncthreads();
#pragma unroll
        for (int kk = 0; kk < BK; kk += 32) {
            const int kb2 = (kk + (lane >> 4) * 8) * 2; // byte col, 16B aligned
            short8 af[MR], bfr[NR];
#pragma unroll
            for (int m = 0; m < MR; ++m) {
                const int r = wr * (BM / 2) + m * 16 + (lane & 15);
                af[m] = *(const short8*)(sA + r * 128 + (kb2 ^ ((r & 7) << 4)));
            }
#pragma unroll
            for (int n = 0; n < NR; ++n) {
                const int r = wc * (BN / 2) + n * 16 + (lane & 15);
                bfr[n] = *(const short8*)(sB + r * 128 + (kb2 ^ ((r & 7) << 4)));
            }
#pragma unroll
            for (int m = 0; m < MR; ++m) {
#pragma unroll
                for (int n = 0; n < NR; ++n) {
                    acc[m][n] = __builtin_amdgcn_mfma_f32_16x16x32_bf16(af[m], bfr[n], acc[m][n], 0, 0, 0);
                }
            }
        }
        __syncthreads();
    }

#pragma unroll
    for (int m = 0; m < MR; ++m) {
#pragma unroll
        for (int n = 0; n < NR; ++n) {
            const int col = n0 + wc * (BN / 2) + n * 16 + (lane & 15);
            const float bv = (EPI == 1) ? bias[col] : 0.f;
#pragma unroll
            for (int j = 0; j < 4; ++j) {
                const int row = m0 + wr * (BM / 2) + m * 16 + (lane >> 4) * 4 + j;
                float v = acc[m][n][j] + bv;
                float* p = C + (size_t)row * ldc + col;
                if (EPI == 2) {
                    atomicAdd(p, v);
                } else {
                    if (EPI == 3) v += *p;
                    *p = v;
                }
            }
        }
    }
}

// ---------------------------------------------------------------------------
// Causal depthwise conv (K=4) + SiLU. Also zeroes dbc (first 128 blocks),
// replacing the hipMemsetAsync before the split-K atomic xp-GEMM.
// ---------------------------------------------------------------------------
__global__ __launch_bounds__(256) void conv_silu_kernel(const float* __restrict__ xz,
                                                        const float* __restrict__ cw,
                                                        const float* __restrict__ cb,
                                                        float* __restrict__ xc,
                                                        bf16* __restrict__ xc_bf,
                                                        float* __restrict__ dbc_zero) {
    if (blockIdx.x < 128) {
        ((float4*)dbc_zero)[blockIdx.x * 256 + threadIdx.x] = make_float4(0.f, 0.f, 0.f, 0.f);
    }
    const int idx = blockIdx.x * 256 + threadIdx.x; // over 2048*1024
    const int c = idx & (DI - 1);
    const int r = idx >> 10;
    const int l = r & (LL - 1);
    const float* xi = xz + (size_t)r * (2 * DI) + c;
    const float4 w = *(const float4*)(cw + (size_t)c * 4);
    float acc = cb[c] + w.w * xi[0];
    if (l >= 1) acc += w.z * xi[-(2 * DI)];
    if (l >= 2) acc += w.y * xi[-(4 * DI)];
    if (l >= 3) acc += w.x * xi[-(6 * DI)];
    const float s = acc / (1.f + expf(-acc)); // silu
    xc[idx] = s;
    xc_bf[idx] = __float2bfloat16(s);
}

// ---------------------------------------------------------------------------
// Selective scan, 3-kernel chunked form; channel in the LANE dimension.
// part1 now also computes delta = softplus(dt @ dt_w^T + dt_b) inline
// (dtw_t is [RK][DI], lane-coalesced; dt rows are wave-uniform broadcasts)
// and stores it for part3. Replaces the dtproj kernel.
// ---------------------------------------------------------------------------
__global__ __launch_bounds__(256) void scan_part1(const float* __restrict__ xc,
                                                  const float* __restrict__ dbc,
                                                  const float* __restrict__ Alog,
                                                  const float* __restrict__ dtw_t,
                                                  const float* __restrict__ dtb,
                                                  float* __restrict__ delta,
                                                  float* __restrict__ psum,
                                                  float* __restrict__ ssum) {
    const int lane = threadIdx.x & 63;
    const int wsub = threadIdx.x >> 6;
    const int c = blockIdx.x * 64 + lane;
    const int chunk = blockIdx.y * 4 + wsub;
    const int b = blockIdx.z;
    const int r0 = b * LL + chunk * CH;

    float wv[RK];
#pragma unroll
    for (int k = 0; k < RK; ++k) wv[k] = dtw_t[(size_t)k * DI + c];
    const float bdt = dtb[c];

    float a2[DSN];
#pragma unroll
    for (int q = 0; q < 4; ++q) {
        const float4 al = *(const float4*)(Alog + (size_t)c * DSN + q * 4);
        a2[q * 4 + 0] = -expf(al.x) * 1.44269504f;
        a2[q * 4 + 1] = -expf(al.y) * 1.44269504f;
        a2[q * 4 + 2] = -expf(al.z) * 1.44269504f;
        a2[q * 4 + 3] = -expf(al.w) * 1.44269504f;
    }

    float h[DSN], P[DSN];
#pragma unroll
    for (int n = 0; n < DSN; ++n) { h[n] = 0.f; P[n] = 1.f; }

    for (int t = 0; t < CH; ++t) {
        const size_t r = r0 + t;
        // delta: dot(dt_row, dtw[c]) + softplus (dt row = broadcast loads)
        float acc = bdt;
#pragma unroll
        for (int q = 0; q < RK / 4; ++q) {
            const float4 d4 = *(const float4*)(dbc + r * 64 + q * 4);
            acc = fmaf(d4.x, wv[q * 4 + 0], acc);
            acc = fmaf(d4.y, wv[q * 4 + 1], acc);
            acc = fmaf(d4.z, wv[q * 4 + 2], acc);
            acc = fmaf(d4.w, wv[q * 4 + 3], acc);
        }
        const float d = (acc > 20.f) ? acc : log1pf(expf(acc));
        delta[r * DI + c] = d;

        const float xv = xc[r * DI + c];
        const float dxv = d * xv;
        float Bv[DSN];
#pragma unroll
        for (int q = 0; q < 4; ++q)
            *(float4*)&Bv[q * 4] = *(const float4*)(dbc + r * 64 + 32 + q * 4);
#pragma unroll
        for (int n = 0; n < DSN; ++n) {
            const float dA = exp2f(d * a2[n]);
            h[n] = fmaf(dA, h[n], dxv * Bv[n]);
            P[n] *= dA;
        }
    }

    const size_t obase = ((size_t)(b * NCHUNK + chunk) * DSN) * DI + c;
#pragma unroll
    for (int n = 0; n < DSN; ++n) {
        psum[obase + (size_t)n * DI] = P[n];
        ssum[obase + (size_t)n * DI] = h[n];
    }
}

__global__ __launch_bounds__(256) void scan_combine(float* __restrict__ psum,
                                                    const float* __restrict__ ssum) {
    const int lane = threadIdx.x & 63;
    const int idx = blockIdx.y * 4 + (threadIdx.x >> 6); // [0,32): b*16+n
    const int b = idx >> 4, n = idx & 15;
    const int c = blockIdx.x * 64 + lane;
    const size_t base = ((size_t)(b * NCHUNK) * DSN + n) * DI + c;
    const size_t stride = (size_t)DSN * DI; // chunk stride

    float h = 0.f;
    for (int j0 = 0; j0 < NCHUNK; j0 += 8) {
        float Pv[8], Sv[8];
#pragma unroll
        for (int u = 0; u < 8; ++u) {
            Pv[u] = psum[base + (j0 + u) * stride];
            Sv[u] = ssum[base + (j0 + u) * stride];
        }
#pragma unroll
        for (int u = 0; u < 8; ++u) {
            psum[base + (j0 + u) * stride] = h; // h_in for chunk j0+u
            h = fmaf(Pv[u], h, Sv[u]);
        }
    }
}

__global__ __launch_bounds__(256) void scan_part3(const float* __restrict__ delta,
                                                  const float* __restrict__ xc,
                                                  const float* __restrict__ xz,
                                                  const float* __restrict__ dbc,
                                                  const float* __restrict__ Alog,
                                                  const float* __restrict__ Dp,
                                                  const float* __restrict__ hin,
                                                  bf16* __restrict__ yg) {
    const int lane = threadIdx.x & 63;
    const int wsub = threadIdx.x >> 6;
    const int c = blockIdx.x * 64 + lane;
    const int chunk = blockIdx.y * 4 + wsub;
    const int b = blockIdx.z;
    const int r0 = b * LL + chunk * CH;

    float a2[DSN];
#pragma unroll
    for (int q = 0; q < 4; ++q) {
        const float4 al = *(const float4*)(Alog + (size_t)c * DSN + q * 4);
        a2[q * 4 + 0] = -expf(al.x) * 1.44269504f;
        a2[q * 4 + 1] = -expf(al.y) * 1.44269504f;
        a2[q * 4 + 2] = -expf(al.z) * 1.44269504f;
        a2[q * 4 + 3] = -expf(al.w) * 1.44269504f;
    }
    const float dp = Dp[c];

    float h[DSN];
    const size_t hbase = ((size_t)(b * NCHUNK + chunk) * DSN) * DI + c;
#pragma unroll
    for (int n = 0; n < DSN; ++n) h[n] = hin[hbase + (size_t)n * DI];

    for (int t = 0; t < CH; ++t) {
        const size_t r = r0 + t;
        const float d  = delta[r * DI + c];
        const float xv = xc[r * DI + c];
        const float zv = xz[r * (2 * DI) + DI + c];
        const float dxv = d * xv;
        float Bv[DSN], Cv[DSN];
#pragma unroll
        for (int q = 0; q < 4; ++q) {
            *(float4*)&Bv[q * 4] = *(const float4*)(dbc + r * 64 + 32 + q * 4);
            *(float4*)&Cv[q * 4] = *(const float4*)(dbc + r * 64 + 48 + q * 4);
        }
        float y0 = 0.f, y1 = 0.f, y2 = 0.f, y3 = 0.f;
#pragma unroll
        for (int q = 0; q < 4; ++q) {
            {
                const float dA = exp2f(d * a2[q * 4 + 0]);
                h[q * 4 + 0] = fmaf(dA, h[q * 4 + 0], dxv * Bv[q * 4 + 0]);
                y0 = fmaf(h[q * 4 + 0], Cv[q * 4 + 0], y0);
            }
            {
                const float dA = exp2f(d * a2[q * 4 + 1]);
                h[q * 4 + 1] = fmaf(dA, h[q * 4 + 1], dxv * Bv[q * 4 + 1]);
                y1 = fmaf(h[q * 4 + 1], Cv[q * 4 + 1], y1);
            }
            {
                const float dA = exp2f(d * a2[q * 4 + 2]);
                h[q * 4 + 2] = fmaf(dA, h[q * 4 + 2], dxv * Bv[q * 4 + 2]);
                y2 = fmaf(h[q * 4 + 2], Cv[q * 4 + 2], y2);
            }
            {
                const float dA = exp2f(d * a2[q * 4 + 3]);
                h[q * 4 + 3] = fmaf(dA, h[q * 4 + 3], dxv * Bv[q * 4 + 3]);
                y3 = fmaf(h[q * 4 + 3], Cv[q * 4 + 3], y3);
            }
        }
        const float y = (y0 + y1) + (y2 + y3);
        const float zs = zv / (1.f + expf(-zv));
        yg[r * DI + c] = __float2bfloat16((y + dp * xv) * zs);
    }
}

// ---------------------------------------------------------------------------
// One Mamba layer (8 dispatches)
// ---------------------------------------------------------------------------
static void run_mamba_layer(hipStream_t stream, float* resid,
                            const float* ln_w, const float* ln_b,
                            const bf16* inw_bf,
                            const float* conv_w, const float* conv_b,
                            const bf16* xpw_bf,
                            const float* dtw_t, const float* dt_b,
                            const float* Alog, const float* Dp,
                            const bf16* outw_bf,
                            bf16* ln_bf, float* xz, float* xc, bf16* xc_bf,
                            float* dbc, float* delta,
                            float* psum, float* ssum, bf16* yg_bf) {
    ln_kernel<bf16><<<MR_ROWS, 256, 0, stream>>>(resid, ln_w, ln_b, ln_bf);
    // xz = ln_out @ in_w^T : M=2048, N=2048, K=512 (64x64 tiles -> 1024 blocks)
    gemm_bt<64, 64, 64, 0><<<dim3(2 * DI / 64, MR_ROWS / 64), 256, 0, stream>>>(
        ln_bf, DM, inw_bf, DM, xz, 2 * DI, DM, nullptr);
    conv_silu_kernel<<<MR_ROWS * DI / 256, 256, 0, stream>>>(xz, conv_w, conv_b, xc, xc_bf, dbc);
    // dbc = xc @ xp_w^T : M=2048, N=64, K=1024, split-K x4 -> 256 blocks
    gemm_bt<32, 64, 64, 2><<<dim3(1, MR_ROWS / 32, 4), 256, 0, stream>>>(
        xc_bf, DI, xpw_bf, DI, dbc, 64, DI / 4, nullptr);
    // 3-kernel chunked scan (part1 fuses the dt projection + softplus)
    scan_part1<<<dim3(DI / 64, NCHUNK / 4, LB), 256, 0, stream>>>(
        xc, dbc, Alog, dtw_t, dt_b, delta, psum, ssum);
    scan_combine<<<dim3(DI / 64, (LB * DSN) / 4), 256, 0, stream>>>(psum, ssum);
    scan_part3<<<dim3(DI / 64, NCHUNK / 4, LB), 256, 0, stream>>>(
        delta, xc, xz, dbc, Alog, Dp, psum, yg_bf);
    // resid += yg @ out_w^T : M=2048, N=512, K=1024 (32x64 -> 512 blocks)
    gemm_bt<32, 64, 64, 3><<<dim3(DM / 64, MR_ROWS / 32), 256, 0, stream>>>(
        yg_bf, DI, outw_bf, DI, resid, DM, DI, nullptr);
}

// ---------------------------------------------------------------------------
extern "C" void kernel_launch(void* const* d_in, const int* in_sizes, int n_in,
                              void* d_out, int out_size, void* d_ws, size_t ws_size,
                              hipStream_t stream) {
    const float* x         = (const float*)d_in[0];
    const float* inp_w     = (const float*)d_in[1];
    const float* inp_b     = (const float*)d_in[2];
    const float* enc_ln_w  = (const float*)d_in[3];
    const float* enc_ln_b  = (const float*)d_in[4];
    const float* enc_in_w  = (const float*)d_in[5];
    const float* enc_conv_w= (const float*)d_in[6];
    const float* enc_conv_b= (const float*)d_in[7];
    const float* enc_xp_w  = (const float*)d_in[8];
    const float* enc_dt_w  = (const float*)d_in[9];
    const float* enc_dt_b  = (const float*)d_in[10];
    const float* enc_Alog  = (const float*)d_in[11];
    const float* enc_D     = (const float*)d_in[12];
    const float* enc_out_w = (const float*)d_in[13];
    const float* fin_ln_w  = (const float*)d_in[14];
    const float* fin_ln_b  = (const float*)d_in[15];
    const float* prd_ln_w  = (const float*)d_in[16];
    const float* prd_ln_b  = (const float*)d_in[17];
    const float* prd_in_w  = (const float*)d_in[18];
    const float* prd_conv_w= (const float*)d_in[19];
    const float* prd_conv_b= (const float*)d_in[20];
    const float* prd_xp_w  = (const float*)d_in[21];
    const float* prd_dt_w  = (const float*)d_in[22];
    const float* prd_dt_b  = (const float*)d_in[23];
    const float* prd_Alog  = (const float*)d_in[24];
    const float* prd_D     = (const float*)d_in[25];
    const float* prd_out_w = (const float*)d_in[26];
    const float* prd_nrm_w = (const float*)d_in[27];
    const float* prd_nrm_b = (const float*)d_in[28];
    const float* prd_proj_w= (const float*)d_in[29];
    const float* prd_proj_b= (const float*)d_in[30];

    char* wp = (char*)d_ws;
    auto carve = [&](size_t elems, size_t esz) {
        void* p = (void*)wp;
        wp += (elems * esz + 255) & ~(size_t)255;
        return p;
    };
    bf16* x_bf     = (bf16*)carve((size_t)MR_ROWS * 128, 2);
    bf16* inpw_bf  = (bf16*)carve((size_t)DM * 128, 2);
    bf16* einw_bf  = (bf16*)carve(4ull * 2 * DI * DM, 2);
    bf16* expw_bf  = (bf16*)carve(4ull * 64 * DI, 2);
    bf16* eoutw_bf = (bf16*)carve(4ull * DM * DI, 2);
    bf16* pinw_bf  = (bf16*)carve(2ull * 2 * DI * DM, 2);
    bf16* pxpw_bf  = (bf16*)carve(2ull * 64 * DI, 2);
    bf16* poutw_bf = (bf16*)carve(2ull * DM * DI, 2);
    bf16* projw_bf = (bf16*)carve((size_t)DM * DM, 2);
    float* dtwt    = (float*)carve(6ull * RK * DI, 4);
    float* hbuf    = (float*)carve((size_t)MR_ROWS * DM, 4);
    float* pbuf    = (float*)carve((size_t)MR_ROWS * DM, 4);
    bf16* ln_bf    = (bf16*)carve((size_t)MR_ROWS * DM, 2);
    float* xz      = (float*)carve((size_t)MR_ROWS * 2 * DI, 4);
    float* xc      = (float*)carve((size_t)MR_ROWS * DI, 4);
    bf16* xc_bf    = (bf16*)carve((size_t)MR_ROWS * DI, 2);
    float* dbc     = (float*)carve((size_t)MR_ROWS * 64, 4);
    float* delta   = (float*)carve((size_t)MR_ROWS * DI, 4);
    float* psum    = (float*)carve((size_t)LB * NCHUNK * DSN * DI, 4);
    float* ssum    = (float*)carve((size_t)LB * NCHUNK * DSN * DI, 4);
    bf16* yg_bf    = (bf16*)carve((size_t)MR_ROWS * DI, 2);

    // --- weight/input conversion to bf16 (one launch) + dtw transpose ---
    ConvArgs ca;
    const float* csrc[9] = {x, inp_w, enc_in_w, enc_xp_w, enc_out_w,
                            prd_in_w, prd_xp_w, prd_out_w, prd_proj_w};
    bf16* cdst[9] = {x_bf, inpw_bf, einw_bf, expw_bf, eoutw_bf,
                     pinw_bf, pxpw_bf, poutw_bf, projw_bf};
    const int cn[9] = {MR_ROWS * 128, DM * 128, 4 * 2 * DI * DM, 4 * 64 * DI, 4 * DM * DI,
                       2 * 2 * DI * DM, 2 * 64 * DI, 2 * DM * DI, DM * DM};
    for (int i = 0; i < 9; ++i) { ca.src[i] = csrc[i]; ca.dst[i] = cdst[i]; ca.n4[i] = cn[i] / 4; }
    convert_bf16_multi<<<dim3(128, 9), 256, 0, stream>>>(ca);
    transpose_dtw<<<dim3(RK * DI / 256, 6), 256, 0, stream>>>(enc_dt_w, prd_dt_w, dtwt);

    // --- input projection: h = x @ inp_w^T + inp_b  (M=2048, N=512, K=128) ---
    gemm_bt<32, 64, 64, 1><<<dim3(DM / 64, MR_ROWS / 32), 256, 0, stream>>>(
        x_bf, 128, inpw_bf, 128, hbuf, DM, 128, inp_b);

    // --- encoder layers ---
    for (int i = 0; i < 4; ++i) {
        run_mamba_layer(stream, hbuf,
                        enc_ln_w + (size_t)i * DM, enc_ln_b + (size_t)i * DM,
                        einw_bf + (size_t)i * 2 * DI * DM,
                        enc_conv_w + (size_t)i * DI * 4, enc_conv_b + (size_t)i * DI,
                        expw_bf + (size_t)i * 64 * DI,
                        dtwt + (size_t)i * RK * DI, enc_dt_b + (size_t)i * DI,
                        enc_Alog + (size_t)i * DI * DSN, enc_D + (size_t)i * DI,
                        eoutw_bf + (size_t)i * DM * DI,
                        ln_bf, xz, xc, xc_bf, dbc, delta, psum, ssum, yg_bf);
    }

    // --- final encoder LN -> predictor stream ---
    ln_kernel<float><<<MR_ROWS, 256, 0, stream>>>(hbuf, fin_ln_w, fin_ln_b, pbuf);

    // --- predictor layers ---
    for (int i = 0; i < 2; ++i) {
        run_mamba_layer(stream, pbuf,
                        prd_ln_w + (size_t)i * DM, prd_ln_b + (size_t)i * DM,
                        pinw_bf + (size_t)i * 2 * DI * DM,
                        prd_conv_w + (size_t)i * DI * 4, prd_conv_b + (size_t)i * DI,
                        pxpw_bf + (size_t)i * 64 * DI,
                        dtwt + (size_t)(4 + i) * RK * DI, prd_dt_b + (size_t)i * DI,
                        prd_Alog + (size_t)i * DI * DSN, prd_D + (size_t)i * DI,
                        poutw_bf + (size_t)i * DM * DI,
                        ln_bf, xz, xc, xc_bf, dbc, delta, psum, ssum, yg_bf);
    }

    // --- final norm + projection ---
    ln_kernel<bf16><<<MR_ROWS, 256, 0, stream>>>(pbuf, prd_nrm_w, prd_nrm_b, ln_bf);
    gemm_bt<32, 64, 64, 1><<<dim3(DM / 64, MR_ROWS / 32), 256, 0, stream>>>(
        ln_bf, DM, projw_bf, DM, (float*)d_out, DM, DM, prd_proj_b);

    (void)in_sizes; (void)n_in; (void)out_size; (void)ws_size;
}